// Round 10
// baseline (3892.303 us; speedup 1.0000x reference)
//
#include <hip/hip_runtime.h>
#include <math.h>

#define N 64
#define NP 65            // odd pitch: row & column phases conflict-free
#define MIN_SWEEPS 4
#define MAX_SWEEPS 8
#define EPSV 1e-3
#define MAXEIG 1000.0
#define SKIP_DELTA 2e-7f // |apq| <= delta -> identity rotation (skippable)
#define OFF_TOL2 9e-10f  // (3e-5)^2: off-diag Frob^2 convergence target

// EIGHT 64-lane waves per 64x64 symmetric matrix (512 threads/block).
// Two-sided cyclic Jacobi, tournament ordering; 32 pairs/round, 4 per wave.
// Round-9 landed in a mixed barrier/dependency regime (VALU 63%, LDS ~50%,
// occupancy 87%) -> this round reduces total work instead of instruction mix:
//  - adaptive sweeps: 4 unconditional, then off-diag Frob check gates sweeps
//    5..8. ||E|| <= off * (1/eps) = 3e-5*1000 = 0.03 worst-case addition.
//    (round 8 failed by stopping blindly at 5 sweeps; this stops by measure.)
//  - wave-uniform skip: |apq| <= 2e-7 -> s = 0; if all 4 pairs of a wave are
//    identity, a SCALAR branch skips the row/col/Vt phases (barriers kept).
//    All-skip state implies off <= sqrt(4032)*2e-7 = 1.3e-5 < 3e-5: no livelock.
__global__ __launch_bounds__(512, 8)
void spd_log_kernel(const float* __restrict__ x, float* __restrict__ out) {
    __shared__ __align__(16) float buf[2 * N * NP];  // [0,64): A ; [64,128): Vt
    __shared__ float farr[N];
    __shared__ int done_flag;

    float* const As_ = buf;
    float* const Vt_ = buf + N * NP;   // Vt row k = eigenvector k

    const int tid  = (int)threadIdx.x;
    const int lane = tid & 63;
    const int wid  = __builtin_amdgcn_readfirstlane(tid >> 6);  // 0..7
    const size_t mat = blockIdx.x;
    const float* __restrict__ xm = x + mat * (size_t)(N * N);
    float* __restrict__ om = out + mat * (size_t)(N * N);

#pragma unroll
    for (int t = 0; t < 8; ++t) {
        const int r2 = wid * 8 + t;
        As_[r2 * NP + lane] = xm[r2 * N + lane];
        Vt_[r2 * NP + lane] = (r2 == lane) ? 1.0f : 0.0f;
    }
    __syncthreads();

    for (int sweep = 0; sweep < MAX_SWEEPS; ++sweep) {
        if (sweep >= MIN_SWEEPS) {
            // ---- convergence check: off-diag Frobenius^2 < OFF_TOL2 ? ----
            float part = 0.0f;
#pragma unroll
            for (int t = 0; t < 8; ++t) {
                const int rr = wid * 8 + t;
                const float a_ = As_[rr * NP + lane];
                part += (rr == lane) ? 0.0f : a_ * a_;
            }
#pragma unroll
            for (int off = 32; off > 0; off >>= 1)
                part += __shfl_down(part, off);
            if (lane == 0) farr[wid] = part;
            __syncthreads();
            if (tid == 0) {
                float s = 0.0f;
#pragma unroll
                for (int k = 0; k < 8; ++k) s += farr[k];
                done_flag = (s < OFF_TOL2) ? 1 : 0;
            }
            __syncthreads();
            if (done_flag) break;
        }

        for (int r = 0; r < N - 1; ++r) {
            // ---- coefficients for this wave's 4 pairs (lanes 0..3);
            //      reads only rows/cols this wave owns -> no barrier ----
            float cv = 1.0f, sv = 0.0f;
            if (lane < 4) {
                const int i = wid * 4 + lane;
                int a = i - 1 + r; if (a >= 63) a -= 63;
                const int p = (i == 0) ? 0 : 1 + a;
                int b = 62 - i + r; if (b >= 63) b -= 63;
                const int q = 1 + b;
                const float app = As_[p * NP + p];
                const float aqq = As_[q * NP + q];
                const float apq = As_[p * NP + q];
                // branchless fast-math rotation coefficients
                const float tau = (aqq - app) * (0.5f * __builtin_amdgcn_rcpf(apq));
                const float at  = fabsf(tau);
                float t2 = __builtin_amdgcn_rcpf(at + __builtin_amdgcn_sqrtf(fmaf(at, at, 1.0f)));
                t2 = copysignf(t2, tau);
                const float cc = __builtin_amdgcn_rsqf(fmaf(t2, t2, 1.0f));
                // |apq| <= SKIP_DELTA (incl. 0 with app==aqq -> NaN): identity
                const bool tiny = !(fabsf(apq) > SKIP_DELTA);
                cv = tiny ? 1.0f : cc;
                sv = tiny ? 0.0f : t2 * cc;
            }
            // (c,s) -> SGPR broadcasts; pair indices -> SALU (wid scalar)
            float ca[4], sa[4];
#pragma unroll
            for (int ii = 0; ii < 4; ++ii) {
                ca[ii] = __uint_as_float(__builtin_amdgcn_readlane(__float_as_uint(cv), ii));
                sa[ii] = __uint_as_float(__builtin_amdgcn_readlane(__float_as_uint(sv), ii));
            }
            // wave-uniform skip: all 4 sines exactly +0.0f
            const bool allskip =
                ((__float_as_uint(sa[0]) | __float_as_uint(sa[1]) |
                  __float_as_uint(sa[2]) | __float_as_uint(sa[3])) == 0u);
            int pa[4], qa[4];
#pragma unroll
            for (int ii = 0; ii < 4; ++ii) {
                const int i = wid * 4 + ii;
                int a = i - 1 + r; if (a >= 63) a -= 63;
                pa[ii] = (i == 0) ? 0 : 1 + a;
                int b = 62 - i + r; if (b >= 63) b -= 63;
                qa[ii] = 1 + b;
            }

            // ---- ROW phase: lane = column; gather all, then write all ----
            if (!allskip) {
                float rp[4], rq[4];
#pragma unroll
                for (int ii = 0; ii < 4; ++ii) {
                    rp[ii] = As_[pa[ii] * NP + lane];
                    rq[ii] = As_[qa[ii] * NP + lane];
                }
#pragma unroll
                for (int ii = 0; ii < 4; ++ii) {
                    As_[pa[ii] * NP + lane] = ca[ii] * rp[ii] - sa[ii] * rq[ii];
                    As_[qa[ii] * NP + lane] = sa[ii] * rp[ii] + ca[ii] * rq[ii];
                }
            }
            __syncthreads();

            // ---- COL phase on A (lane = row) + Vt rotation (wave-own rows;
            //      Vt addr = row-phase addr + const offset -> imm folded) ----
            if (!allskip) {
                float cp[4], cq[4], vp[4], vq[4];
#pragma unroll
                for (int ii = 0; ii < 4; ++ii) {
                    cp[ii] = As_[lane * NP + pa[ii]];
                    cq[ii] = As_[lane * NP + qa[ii]];
                    vp[ii] = Vt_[pa[ii] * NP + lane];
                    vq[ii] = Vt_[qa[ii] * NP + lane];
                }
#pragma unroll
                for (int ii = 0; ii < 4; ++ii) {
                    As_[lane * NP + pa[ii]] = ca[ii] * cp[ii] - sa[ii] * cq[ii];
                    As_[lane * NP + qa[ii]] = sa[ii] * cp[ii] + ca[ii] * cq[ii];
                    Vt_[pa[ii] * NP + lane] = ca[ii] * vp[ii] - sa[ii] * vq[ii];
                    Vt_[qa[ii] * NP + lane] = sa[ii] * vp[ii] + ca[ii] * vq[ii];
                }
            }
            __syncthreads();
        }
    }

    // A is dead from here -> overlay Rayleigh partials on its storage.
    double2* part = reinterpret_cast<double2*>(As_);  // 7*64*16 B < 16.6 KB

    // ---- fp64 Rayleigh vs ORIGINAL input; eigvec `lane` = Vt row `lane`;
    //      each wave covers 8 rows of the quadratic form ----
    const int r0 = wid * 8;
    {
        float vr[8];
#pragma unroll
        for (int t = 0; t < 8; ++t) vr[t] = Vt_[lane * NP + r0 + t];
        double nrm = 0.0, acc = 0.0;
#pragma unroll
        for (int t = 0; t < 8; ++t) nrm += (double)vr[t] * (double)vr[t];
        for (int c = 0; c < N; ++c) {
            const double vc = (double)Vt_[lane * NP + c];
            double inner = 0.0;
#pragma unroll
            for (int t = 0; t < 8; ++t)
                inner += (double)xm[(r0 + t) * N + c] * (double)vr[t];
            acc += vc * inner;
        }
        if (wid > 0) part[(wid - 1) * N + lane] = make_double2(acc, nrm);
        __syncthreads();
        if (wid == 0) {
#pragma unroll
            for (int k = 0; k < 7; ++k) {
                acc += part[k * N + lane].x;
                nrm += part[k * N + lane].y;
            }
            double wv = acc / nrm;
            wv = fmin(fmax(wv, (double)EPSV), (double)MAXEIG);
            farr[lane] = (float)log(wv);
        }
    }
    __syncthreads();

    // ---- reconstruct Out[r][lane] = sum_j Vt[j][r] * f_j * Vt[j][lane];
    //      8 rows per wave; Vt[j][r0+t] is a uniform broadcast read ----
    {
        float acc8[8];
#pragma unroll
        for (int t = 0; t < 8; ++t) acc8[t] = 0.0f;
        for (int j = 0; j < N; ++j) {
            const float gj = Vt_[j * NP + lane] * farr[j];
#pragma unroll
            for (int t = 0; t < 8; ++t)
                acc8[t] += Vt_[j * NP + r0 + t] * gj;
        }
#pragma unroll
        for (int t = 0; t < 8; ++t)
            om[(r0 + t) * N + lane] = acc8[t];
    }
}

extern "C" void kernel_launch(void* const* d_in, const int* in_sizes, int n_in,
                              void* d_out, int out_size, void* d_ws, size_t ws_size,
                              hipStream_t stream) {
    const float* x = (const float*)d_in[0];
    float* out = (float*)d_out;
    const int nmat = in_sizes[0] / (N * N);
    spd_log_kernel<<<dim3(nmat), dim3(512), 0, stream>>>(x, out);
}

// Round 11
// 3371.909 us; speedup vs baseline: 1.1543x; 1.1543x over previous
//
#include <hip/hip_runtime.h>
#include <math.h>

#define N 64
#define NP 66            // even pitch: rows 8B-aligned for float2; col access 2-way (free)
#define NPH 33           // pitch in float2 units
#define SWEEPS 6         // 5 sweeps FAILED (r8, absmax 0.30); adaptive check cost > savings (r10)
#define EPSV 1e-3
#define MAXEIG 1000.0

// EIGHT 64-lane waves per 64x64 symmetric matrix (512 threads/block).
// Two-sided cyclic Jacobi, tournament ordering; 32 pairs/round, 4 per wave.
// Round-9 regime: VALU ~63%, LDS read-port ~61%, occupancy at the 2048-thread
// cap -> dependency/issue-stall bound. Round-11 cuts issue slots and balances
// the two barrier phases:
//  - float2 (ds_*_b64) row & Vt rotations: half-wave per pair, 2 adjacent
//    cols/lane; consecutive lanes touch consecutive 8B -> conflict-free
//    (round 6's conflict disaster was two separate stride-2 b32 ops, not b64).
//  - phase balance: Vt pairs {0,1} rotated in phase 1, {2,3} in phase 2
//    (was 19 vs 32 LDS ops; now ~27 vs ~24).
//  - gather-all-then-write-all kept everywhere (incl. Vt gathers before A
//    writes) so the compiler doesn't serialize on unprovable LDS aliasing.
__global__ __launch_bounds__(512, 8)
void spd_log_kernel(const float* __restrict__ x, float* __restrict__ out) {
    __shared__ __align__(16) float buf[2 * N * NP];  // [0,64): A ; [64,128): Vt
    __shared__ float farr[N];

    float* const As_ = buf;
    float* const Vt_ = buf + N * NP;   // Vt row k = eigenvector k
    float2* const As2 = reinterpret_cast<float2*>(buf);
    float2* const Vt2 = reinterpret_cast<float2*>(buf + N * NP);

    const int tid  = (int)threadIdx.x;
    const int lane = tid & 63;
    const int wid  = __builtin_amdgcn_readfirstlane(tid >> 6);  // 0..7
    const int half = lane >> 5;        // which pair of the float2 group
    const int cl   = lane & 31;        // float2 column index
    const size_t mat = blockIdx.x;
    const float* __restrict__ xm = x + mat * (size_t)(N * N);
    float* __restrict__ om = out + mat * (size_t)(N * N);

#pragma unroll
    for (int t = 0; t < 8; ++t) {
        const int r2 = wid * 8 + t;
        As_[r2 * NP + lane] = xm[r2 * N + lane];
        Vt_[r2 * NP + lane] = (r2 == lane) ? 1.0f : 0.0f;
    }
    __syncthreads();

    for (int sweep = 0; sweep < SWEEPS; ++sweep) {
        for (int r = 0; r < N - 1; ++r) {
            // ---- coefficients for this wave's 4 pairs (lanes 0..3);
            //      reads only rows/cols this wave owns -> no barrier ----
            float cv = 1.0f, sv = 0.0f;
            if (lane < 4) {
                const int i = wid * 4 + lane;
                int a = i - 1 + r; if (a >= 63) a -= 63;
                const int p = (i == 0) ? 0 : 1 + a;
                int b = 62 - i + r; if (b >= 63) b -= 63;
                const int q = 1 + b;
                const float app = As_[p * NP + p];
                const float aqq = As_[q * NP + q];
                const float apq = As_[p * NP + q];
                // branchless fast-math rotation coefficients
                const float tau = (aqq - app) * (0.5f * __builtin_amdgcn_rcpf(apq));
                const float at  = fabsf(tau);
                float t2 = __builtin_amdgcn_rcpf(at + __builtin_amdgcn_sqrtf(fmaf(at, at, 1.0f)));
                t2 = copysignf(t2, tau);
                const float cc = __builtin_amdgcn_rsqf(fmaf(t2, t2, 1.0f));
                const bool tiny = !(fabsf(apq) > 1e-30f);
                cv = tiny ? 1.0f : cc;
                sv = tiny ? 0.0f : t2 * cc;
            }
            // (c,s) -> SGPR broadcasts; pair indices for col phase -> SALU
            float ca[4], sa[4];
#pragma unroll
            for (int ii = 0; ii < 4; ++ii) {
                ca[ii] = __uint_as_float(__builtin_amdgcn_readlane(__float_as_uint(cv), ii));
                sa[ii] = __uint_as_float(__builtin_amdgcn_readlane(__float_as_uint(sv), ii));
            }
            int pa[4], qa[4];
#pragma unroll
            for (int ii = 0; ii < 4; ++ii) {
                const int i = wid * 4 + ii;
                int a = i - 1 + r; if (a >= 63) a -= 63;
                pa[ii] = (i == 0) ? 0 : 1 + a;
                int b = 62 - i + r; if (b >= 63) b -= 63;
                qa[ii] = 1 + b;
            }
            // per-lane pair indices/coeffs for the two float2 groups:
            // group g handles pair i = wid*4 + 2g + half on this lane
            int pg[2], qg[2];
            float cg[2], sg[2];
#pragma unroll
            for (int g = 0; g < 2; ++g) {
                const int i = wid * 4 + 2 * g + half;
                int a = i - 1 + r; if (a >= 63) a -= 63;
                pg[g] = (i == 0) ? 0 : 1 + a;
                int b = 62 - i + r; if (b >= 63) b -= 63;
                qg[g] = 1 + b;
                cg[g] = half ? ca[2 * g + 1] : ca[2 * g];
                sg[g] = half ? sa[2 * g + 1] : sa[2 * g];
            }

            // ---- PHASE 1: A row rotation (both groups, b64) + Vt group 0.
            //      gather all 6 float2 first, then write all 6 ----
            {
                const float2 rp0 = As2[pg[0] * NPH + cl];
                const float2 rq0 = As2[qg[0] * NPH + cl];
                const float2 rp1 = As2[pg[1] * NPH + cl];
                const float2 rq1 = As2[qg[1] * NPH + cl];
                const float2 vp0 = Vt2[pg[0] * NPH + cl];
                const float2 vq0 = Vt2[qg[0] * NPH + cl];
                float2 w;
                w.x = cg[0] * rp0.x - sg[0] * rq0.x;
                w.y = cg[0] * rp0.y - sg[0] * rq0.y;
                As2[pg[0] * NPH + cl] = w;
                w.x = sg[0] * rp0.x + cg[0] * rq0.x;
                w.y = sg[0] * rp0.y + cg[0] * rq0.y;
                As2[qg[0] * NPH + cl] = w;
                w.x = cg[1] * rp1.x - sg[1] * rq1.x;
                w.y = cg[1] * rp1.y - sg[1] * rq1.y;
                As2[pg[1] * NPH + cl] = w;
                w.x = sg[1] * rp1.x + cg[1] * rq1.x;
                w.y = sg[1] * rp1.y + cg[1] * rq1.y;
                As2[qg[1] * NPH + cl] = w;
                w.x = cg[0] * vp0.x - sg[0] * vq0.x;
                w.y = cg[0] * vp0.y - sg[0] * vq0.y;
                Vt2[pg[0] * NPH + cl] = w;
                w.x = sg[0] * vp0.x + cg[0] * vq0.x;
                w.y = sg[0] * vp0.y + cg[0] * vq0.y;
                Vt2[qg[0] * NPH + cl] = w;
            }
            __syncthreads();

            // ---- PHASE 2: A col rotation (4 pairs, b32) + Vt group 1.
            //      gather all, then write all ----
            {
                float cp[4], cq[4];
#pragma unroll
                for (int ii = 0; ii < 4; ++ii) {
                    cp[ii] = As_[lane * NP + pa[ii]];
                    cq[ii] = As_[lane * NP + qa[ii]];
                }
                const float2 vp1 = Vt2[pg[1] * NPH + cl];
                const float2 vq1 = Vt2[qg[1] * NPH + cl];
#pragma unroll
                for (int ii = 0; ii < 4; ++ii) {
                    As_[lane * NP + pa[ii]] = ca[ii] * cp[ii] - sa[ii] * cq[ii];
                    As_[lane * NP + qa[ii]] = sa[ii] * cp[ii] + ca[ii] * cq[ii];
                }
                float2 w;
                w.x = cg[1] * vp1.x - sg[1] * vq1.x;
                w.y = cg[1] * vp1.y - sg[1] * vq1.y;
                Vt2[pg[1] * NPH + cl] = w;
                w.x = sg[1] * vp1.x + cg[1] * vq1.x;
                w.y = sg[1] * vp1.y + cg[1] * vq1.y;
                Vt2[qg[1] * NPH + cl] = w;
            }
            __syncthreads();
        }
    }

    // A is dead from here -> overlay Rayleigh partials on its storage.
    double2* part = reinterpret_cast<double2*>(As_);  // 7*64*16 B < 16.9 KB

    // ---- fp64 Rayleigh vs ORIGINAL input; eigvec `lane` = Vt row `lane`;
    //      each wave covers 8 rows of the quadratic form ----
    const int r0 = wid * 8;
    {
        float vr[8];
#pragma unroll
        for (int t = 0; t < 8; ++t) vr[t] = Vt_[lane * NP + r0 + t];
        double nrm = 0.0, acc = 0.0;
#pragma unroll
        for (int t = 0; t < 8; ++t) nrm += (double)vr[t] * (double)vr[t];
        for (int c = 0; c < N; ++c) {
            const double vc = (double)Vt_[lane * NP + c];
            double inner = 0.0;
#pragma unroll
            for (int t = 0; t < 8; ++t)
                inner += (double)xm[(r0 + t) * N + c] * (double)vr[t];
            acc += vc * inner;
        }
        if (wid > 0) part[(wid - 1) * N + lane] = make_double2(acc, nrm);
        __syncthreads();
        if (wid == 0) {
#pragma unroll
            for (int k = 0; k < 7; ++k) {
                acc += part[k * N + lane].x;
                nrm += part[k * N + lane].y;
            }
            double wv = acc / nrm;
            wv = fmin(fmax(wv, (double)EPSV), (double)MAXEIG);
            farr[lane] = (float)log(wv);
        }
    }
    __syncthreads();

    // ---- reconstruct Out[r][lane] = sum_j Vt[j][r] * f_j * Vt[j][lane];
    //      8 rows per wave; Vt[j][r0+t] is a uniform broadcast read ----
    {
        float acc8[8];
#pragma unroll
        for (int t = 0; t < 8; ++t) acc8[t] = 0.0f;
        for (int j = 0; j < N; ++j) {
            const float gj = Vt_[j * NP + lane] * farr[j];
#pragma unroll
            for (int t = 0; t < 8; ++t)
                acc8[t] += Vt_[j * NP + r0 + t] * gj;
        }
#pragma unroll
        for (int t = 0; t < 8; ++t)
            om[(r0 + t) * N + lane] = acc8[t];
    }
}

extern "C" void kernel_launch(void* const* d_in, const int* in_sizes, int n_in,
                              void* d_out, int out_size, void* d_ws, size_t ws_size,
                              hipStream_t stream) {
    const float* x = (const float*)d_in[0];
    float* out = (float*)d_out;
    const int nmat = in_sizes[0] / (N * N);
    spd_log_kernel<<<dim3(nmat), dim3(512), 0, stream>>>(x, out);
}